// Round 10
// baseline (136.018 us; speedup 1.0000x reference)
//
#include <hip/hip_runtime.h>

typedef _Float16 f16x8  __attribute__((ext_vector_type(8)));
typedef float    f32x16 __attribute__((ext_vector_type(16)));

static constexpr int BATCH = 4;
static constexpr int NPTS  = 8192;
static constexpr int NPROB = 2 * BATCH;       // (batch, direction) = 8
static constexpr int RR    = 8;               // ref chunks per problem
static constexpr int RBLK  = NPTS / RR;       // 1024 refs staged per block (16 KB)
static constexpr int TPB   = 256;             // 4 waves
static constexpr int WQ    = 128;             // queries per wave (4 MFMA col-groups)
static constexpr int QBLK  = (TPB / 64) * WQ; // 512 queries per block
static constexpr int NQB   = NPTS / QBLK;     // 16 query tiles
static constexpr int NBLOCKS = NQB * RR * NPROB;       // 1024
static constexpr int SLOTS   = NPROB * NPTS;           // 65536 per-query min slots
static constexpr unsigned CNT_INIT = 0x7F7F7F7Fu;      // memset(0x7F) pattern
static constexpr unsigned CNT_LAST = CNT_INIT + (unsigned)NBLOCKS - 1u;

__device__ __forceinline__ unsigned packh2(_Float16 lo, _Float16 hi) {
    union { _Float16 h[2]; unsigned u; } v;
    v.h[0] = lo; v.h[1] = hi;
    return v.u;
}

// ---- fused: per-(qtile, refchunk, prob) NN min via MFMA -> atomicMin slots;
// ---- last-arriving block folds+sums all slots -> out[0] (deterministic).
__global__ __launch_bounds__(TPB, 4) void cd_fused(const float* __restrict__ gen,
                                                   const float* __restrict__ train,
                                                   int* __restrict__ slot,
                                                   unsigned* __restrict__ cnt,
                                                   float* __restrict__ out) {
    __shared__ uint4 rA[RBLK];                // 16 KB packed refs (order-scrambled: min-safe)
    const int qb = blockIdx.x, rr = blockIdx.y, prob = blockIdx.z;
    const int b = prob >> 1, dir = prob & 1;
    const float* qbase = (dir == 0 ? gen : train) + (size_t)b * NPTS * 3;
    const float* rbase = (dir == 0 ? train : gen) + (size_t)b * NPTS * 3;
    const int lane = threadIdx.x & 63, wave = threadIdx.x >> 6;

    // Stage+pack: thread t loads 4 consecutive points (12 floats, float4-aligned),
    // writes TRANSPOSED rA[i*256+t] -> consecutive lanes hit consecutive 16B slots
    // (conflict-free ds_write_b128). Point order in LDS is permuted - fine for min.
    {
        const float4* s4 = (const float4*)(rbase + rr * (RBLK * 3)) + threadIdx.x * 3;
        const float4 v0 = s4[0], v1 = s4[1], v2 = s4[2];
        const float px[4] = {v0.x, v0.w, v1.z, v2.y};
        const float py[4] = {v0.y, v1.x, v1.w, v2.z};
        const float pz[4] = {v0.z, v1.y, v2.x, v2.w};
        #pragma unroll
        for (int i = 0; i < 4; ++i) {
            const _Float16 hx = (_Float16)px[i], hy = (_Float16)py[i], hz = (_Float16)pz[i];
            const float xr = (float)hx, yr = (float)hy, zr = (float)hz;   // exact
            const float yy = fmaf(xr, xr, fmaf(yr, yr, zr * zr));
            const _Float16 yh = (_Float16)yy;
            const _Float16 yl = (_Float16)(yy - (float)yh);               // hi/lo split
            rA[i * TPB + threadIdx.x] =
                make_uint4(packh2((_Float16)(-2.0f * xr), (_Float16)(-2.0f * yr)),
                           packh2((_Float16)(-2.0f * zr), yh),
                           packh2(yl, (_Float16)0.0f), 0u);
        }
    }

    // Four query fragments per wave: 32 queries each; B k-vec = [qx,qy,qz,1,1,0,0,0]
    const int qid0 = qb * QBLK + wave * WQ + (lane & 31);
    const int qid1 = qid0 + 32, qid2 = qid0 + 64, qid3 = qid0 + 96;
    float qq0 = 0.0f, qq1 = 0.0f, qq2 = 0.0f, qq3 = 0.0f;
    union { uint4 u; f16x8 h; } B0, B1, B2, B3;
    B0.u = make_uint4(0u, 0u, 0u, 0u);
    B1.u = make_uint4(0u, 0u, 0u, 0u);
    B2.u = make_uint4(0u, 0u, 0u, 0u);
    B3.u = make_uint4(0u, 0u, 0u, 0u);
    if (lane < 32) {
        {
            const float qx = qbase[qid0*3+0], qy = qbase[qid0*3+1], qz = qbase[qid0*3+2];
            const _Float16 hx = (_Float16)qx, hy = (_Float16)qy, hz = (_Float16)qz;
            const float xr = (float)hx, yr = (float)hy, zr = (float)hz;
            qq0  = fmaf(xr, xr, fmaf(yr, yr, zr * zr));
            B0.u = make_uint4(packh2(hx, hy),
                              packh2(hz, (_Float16)0.0f) | 0x3C000000u, 0x3C00u, 0u);
        }
        {
            const float qx = qbase[qid1*3+0], qy = qbase[qid1*3+1], qz = qbase[qid1*3+2];
            const _Float16 hx = (_Float16)qx, hy = (_Float16)qy, hz = (_Float16)qz;
            const float xr = (float)hx, yr = (float)hy, zr = (float)hz;
            qq1  = fmaf(xr, xr, fmaf(yr, yr, zr * zr));
            B1.u = make_uint4(packh2(hx, hy),
                              packh2(hz, (_Float16)0.0f) | 0x3C000000u, 0x3C00u, 0u);
        }
        {
            const float qx = qbase[qid2*3+0], qy = qbase[qid2*3+1], qz = qbase[qid2*3+2];
            const _Float16 hx = (_Float16)qx, hy = (_Float16)qy, hz = (_Float16)qz;
            const float xr = (float)hx, yr = (float)hy, zr = (float)hz;
            qq2  = fmaf(xr, xr, fmaf(yr, yr, zr * zr));
            B2.u = make_uint4(packh2(hx, hy),
                              packh2(hz, (_Float16)0.0f) | 0x3C000000u, 0x3C00u, 0u);
        }
        {
            const float qx = qbase[qid3*3+0], qy = qbase[qid3*3+1], qz = qbase[qid3*3+2];
            const _Float16 hx = (_Float16)qx, hy = (_Float16)qy, hz = (_Float16)qz;
            const float xr = (float)hx, yr = (float)hy, zr = (float)hz;
            qq3  = fmaf(xr, xr, fmaf(yr, yr, zr * zr));
            B3.u = make_uint4(packh2(hx, hy),
                              packh2(hz, (_Float16)0.0f) | 0x3C000000u, 0x3C00u, 0u);
        }
    }
    __syncthreads();

    // 32 tiles: 1 ds_read_b128 feeds 4 MFMAs; fminf-pair folds (compiler fuses to v_min3)
    float m0A = 3.4e38f, m0B = 3.4e38f, m1A = 3.4e38f, m1B = 3.4e38f;
    float m2A = 3.4e38f, m2B = 3.4e38f, m3A = 3.4e38f, m3B = 3.4e38f;
    const int c = lane & 31;
    const f32x16 zc = {};
    #pragma unroll 4
    for (int t = 0; t < RBLK / 32; ++t) {
        union { uint4 u; f16x8 h; } A;
        A.u = rA[t * 32 + c];
        f32x16 d0 = __builtin_amdgcn_mfma_f32_32x32x16_f16(A.h, B0.h, zc, 0, 0, 0);
        f32x16 d1 = __builtin_amdgcn_mfma_f32_32x32x16_f16(A.h, B1.h, zc, 0, 0, 0);
        f32x16 d2 = __builtin_amdgcn_mfma_f32_32x32x16_f16(A.h, B2.h, zc, 0, 0, 0);
        f32x16 d3 = __builtin_amdgcn_mfma_f32_32x32x16_f16(A.h, B3.h, zc, 0, 0, 0);
        m0A = fminf(fminf(d0[0],  d0[1]),  m0A);
        m0A = fminf(fminf(d0[2],  d0[3]),  m0A);
        m0A = fminf(fminf(d0[4],  d0[5]),  m0A);
        m0A = fminf(fminf(d0[6],  d0[7]),  m0A);
        m0B = fminf(fminf(d0[8],  d0[9]),  m0B);
        m0B = fminf(fminf(d0[10], d0[11]), m0B);
        m0B = fminf(fminf(d0[12], d0[13]), m0B);
        m0B = fminf(fminf(d0[14], d0[15]), m0B);
        m1A = fminf(fminf(d1[0],  d1[1]),  m1A);
        m1A = fminf(fminf(d1[2],  d1[3]),  m1A);
        m1A = fminf(fminf(d1[4],  d1[5]),  m1A);
        m1A = fminf(fminf(d1[6],  d1[7]),  m1A);
        m1B = fminf(fminf(d1[8],  d1[9]),  m1B);
        m1B = fminf(fminf(d1[10], d1[11]), m1B);
        m1B = fminf(fminf(d1[12], d1[13]), m1B);
        m1B = fminf(fminf(d1[14], d1[15]), m1B);
        m2A = fminf(fminf(d2[0],  d2[1]),  m2A);
        m2A = fminf(fminf(d2[2],  d2[3]),  m2A);
        m2A = fminf(fminf(d2[4],  d2[5]),  m2A);
        m2A = fminf(fminf(d2[6],  d2[7]),  m2A);
        m2B = fminf(fminf(d2[8],  d2[9]),  m2B);
        m2B = fminf(fminf(d2[10], d2[11]), m2B);
        m2B = fminf(fminf(d2[12], d2[13]), m2B);
        m2B = fminf(fminf(d2[14], d2[15]), m2B);
        m3A = fminf(fminf(d3[0],  d3[1]),  m3A);
        m3A = fminf(fminf(d3[2],  d3[3]),  m3A);
        m3A = fminf(fminf(d3[4],  d3[5]),  m3A);
        m3A = fminf(fminf(d3[6],  d3[7]),  m3A);
        m3B = fminf(fminf(d3[8],  d3[9]),  m3B);
        m3B = fminf(fminf(d3[10], d3[11]), m3B);
        m3B = fminf(fminf(d3[12], d3[13]), m3B);
        m3B = fminf(fminf(d3[14], d3[15]), m3B);
    }
    float m0 = fminf(m0A, m0B);
    float m1 = fminf(m1A, m1B);
    float m2 = fminf(m2A, m2B);
    float m3 = fminf(m3A, m3B);
    m0 = fminf(m0, __shfl_xor(m0, 32));       // fold the two 16-row halves
    m1 = fminf(m1, __shfl_xor(m1, 32));
    m2 = fminf(m2, __shfl_xor(m2, 32));
    m3 = fminf(m3, __shfl_xor(m3, 32));
    if (lane < 32) {
        int* dst = slot + prob * NPTS;
        // clamp >= 0: positive-float int ordering exact for atomicMin (order-independent)
        atomicMin(&dst[qid0], __float_as_int(fmaxf(m0 + qq0, 0.0f)));
        atomicMin(&dst[qid1], __float_as_int(fmaxf(m1 + qq1, 0.0f)));
        atomicMin(&dst[qid2], __float_as_int(fmaxf(m2 + qq2, 0.0f)));
        atomicMin(&dst[qid3], __float_as_int(fmaxf(m3 + qq3, 0.0f)));
    }

    // ---- last-block finalize: fold all slots -> loss ----
    __threadfence();                           // release our atomicMins
    __shared__ unsigned lastflag;
    if (threadIdx.x == 0)
        lastflag = (atomicAdd(cnt, 1u) == CNT_LAST) ? 1u : 0u;
    __syncthreads();
    if (lastflag) {
        __threadfence();                       // acquire side of the cnt handshake
        float s = 0.0f;
        for (int j = threadIdx.x; j < SLOTS; j += TPB) {   // 256 coalesced loads/thread
            int v = __hip_atomic_load(slot + j, __ATOMIC_RELAXED, __HIP_MEMORY_SCOPE_AGENT);
            s += __int_as_float(v);            // fixed per-thread order -> deterministic
        }
        #pragma unroll
        for (int off = 32; off >= 1; off >>= 1) s += __shfl_down(s, off, 64);
        __shared__ float w[4];
        if (lane == 0) w[wave] = s;
        __syncthreads();
        if (threadIdx.x == 0)
            out[0] = ((w[0] + w[1]) + (w[2] + w[3])) * (0.5f / BATCH);
    }
}

extern "C" void kernel_launch(void* const* d_in, const int* in_sizes, int n_in,
                              void* d_out, int out_size, void* d_ws, size_t ws_size,
                              hipStream_t stream) {
    const float* gen   = (const float*)d_in[0];   // [4,8192,3] f32
    const float* train = (const float*)d_in[1];   // [4,8192,3] f32
    char* ws = (char*)d_ws;
    int*      slot = (int*)ws;                         // 65536 slots (256 KB)
    unsigned* cnt  = (unsigned*)(ws + (size_t)SLOTS * 4);
    float*    out  = (float*)d_out;

    // one memset initializes BOTH: slots -> 0x7F7F7F7F (=3.39e38f, +inf-like)
    // and cnt -> CNT_INIT (known constant, so no separate zeroing kernel needed)
    hipMemsetAsync(ws, 0x7F, (size_t)SLOTS * 4 + 4, stream);
    cd_fused<<<dim3(NQB, RR, NPROB), TPB, 0, stream>>>(gen, train, slot, cnt, out);
}

// Round 11
// 24.743 us; speedup vs baseline: 5.4972x; 5.4972x over previous
//
#include <hip/hip_runtime.h>

typedef _Float16 f16x8  __attribute__((ext_vector_type(8)));
typedef float    f32x16 __attribute__((ext_vector_type(16)));

static constexpr int BATCH = 4;
static constexpr int NPTS  = 8192;
static constexpr int NPROB = 2 * BATCH;       // (batch, direction) = 8
static constexpr int RR    = 8;               // ref chunks per problem
static constexpr int RBLK  = NPTS / RR;       // 1024 refs staged per block (16 KB)
static constexpr int TPB   = 256;             // 4 waves
static constexpr int WQ    = 128;             // queries per wave (4 MFMA col-groups)
static constexpr int QBLK  = (TPB / 64) * WQ; // 512 queries per block
static constexpr int NQB   = NPTS / QBLK;     // 16 query tiles

__device__ __forceinline__ unsigned packh2(_Float16 lo, _Float16 hi) {
    union { _Float16 h[2]; unsigned u; } v;
    v.h[0] = lo; v.h[1] = hi;
    return v.u;
}

// ---------------- pass 1: per-(qtile, refchunk, prob) partial NN min via MFMA ----------------
__global__ __launch_bounds__(TPB, 4) void cd_pass1(const float* __restrict__ gen,
                                                   const float* __restrict__ train,
                                                   float* __restrict__ pmin,
                                                   unsigned long long* __restrict__ acc,
                                                   unsigned* __restrict__ cnt) {
    __shared__ uint4 rA[RBLK];                // 16 KB packed refs (order-scrambled: min-safe)
    const int qb = blockIdx.x, rr = blockIdx.y, prob = blockIdx.z;
    if (qb == 0 && rr == 0 && prob == 0 && threadIdx.x == 0) { *acc = 0ull; *cnt = 0u; }
    const int b = prob >> 1, dir = prob & 1;
    const float* qbase = (dir == 0 ? gen : train) + (size_t)b * NPTS * 3;
    const float* rbase = (dir == 0 ? train : gen) + (size_t)b * NPTS * 3;
    const int lane = threadIdx.x & 63, wave = threadIdx.x >> 6;

    // Stage+pack: thread t loads 4 consecutive points (12 floats, float4-aligned),
    // writes TRANSPOSED rA[i*256+t] -> consecutive lanes hit consecutive 16B slots
    // (conflict-free ds_write_b128). Point order in LDS is permuted - fine for min.
    {
        const float4* s4 = (const float4*)(rbase + rr * (RBLK * 3)) + threadIdx.x * 3;
        const float4 v0 = s4[0], v1 = s4[1], v2 = s4[2];
        const float px[4] = {v0.x, v0.w, v1.z, v2.y};
        const float py[4] = {v0.y, v1.x, v1.w, v2.z};
        const float pz[4] = {v0.z, v1.y, v2.x, v2.w};
        #pragma unroll
        for (int i = 0; i < 4; ++i) {
            const _Float16 hx = (_Float16)px[i], hy = (_Float16)py[i], hz = (_Float16)pz[i];
            const float xr = (float)hx, yr = (float)hy, zr = (float)hz;   // exact
            const float yy = fmaf(xr, xr, fmaf(yr, yr, zr * zr));
            const _Float16 yh = (_Float16)yy;
            const _Float16 yl = (_Float16)(yy - (float)yh);               // hi/lo split
            rA[i * TPB + threadIdx.x] =
                make_uint4(packh2((_Float16)(-2.0f * xr), (_Float16)(-2.0f * yr)),
                           packh2((_Float16)(-2.0f * zr), yh),
                           packh2(yl, (_Float16)0.0f), 0u);
        }
    }

    // Four query fragments per wave: 32 queries each; B k-vec = [qx,qy,qz,1,1,0,0,0]
    const int qid0 = qb * QBLK + wave * WQ + (lane & 31);
    const int qid1 = qid0 + 32, qid2 = qid0 + 64, qid3 = qid0 + 96;
    float qq0 = 0.0f, qq1 = 0.0f, qq2 = 0.0f, qq3 = 0.0f;
    union { uint4 u; f16x8 h; } B0, B1, B2, B3;
    B0.u = make_uint4(0u, 0u, 0u, 0u);
    B1.u = make_uint4(0u, 0u, 0u, 0u);
    B2.u = make_uint4(0u, 0u, 0u, 0u);
    B3.u = make_uint4(0u, 0u, 0u, 0u);
    if (lane < 32) {
        {
            const float qx = qbase[qid0*3+0], qy = qbase[qid0*3+1], qz = qbase[qid0*3+2];
            const _Float16 hx = (_Float16)qx, hy = (_Float16)qy, hz = (_Float16)qz;
            const float xr = (float)hx, yr = (float)hy, zr = (float)hz;
            qq0  = fmaf(xr, xr, fmaf(yr, yr, zr * zr));
            B0.u = make_uint4(packh2(hx, hy),
                              packh2(hz, (_Float16)0.0f) | 0x3C000000u, 0x3C00u, 0u);
        }
        {
            const float qx = qbase[qid1*3+0], qy = qbase[qid1*3+1], qz = qbase[qid1*3+2];
            const _Float16 hx = (_Float16)qx, hy = (_Float16)qy, hz = (_Float16)qz;
            const float xr = (float)hx, yr = (float)hy, zr = (float)hz;
            qq1  = fmaf(xr, xr, fmaf(yr, yr, zr * zr));
            B1.u = make_uint4(packh2(hx, hy),
                              packh2(hz, (_Float16)0.0f) | 0x3C000000u, 0x3C00u, 0u);
        }
        {
            const float qx = qbase[qid2*3+0], qy = qbase[qid2*3+1], qz = qbase[qid2*3+2];
            const _Float16 hx = (_Float16)qx, hy = (_Float16)qy, hz = (_Float16)qz;
            const float xr = (float)hx, yr = (float)hy, zr = (float)hz;
            qq2  = fmaf(xr, xr, fmaf(yr, yr, zr * zr));
            B2.u = make_uint4(packh2(hx, hy),
                              packh2(hz, (_Float16)0.0f) | 0x3C000000u, 0x3C00u, 0u);
        }
        {
            const float qx = qbase[qid3*3+0], qy = qbase[qid3*3+1], qz = qbase[qid3*3+2];
            const _Float16 hx = (_Float16)qx, hy = (_Float16)qy, hz = (_Float16)qz;
            const float xr = (float)hx, yr = (float)hy, zr = (float)hz;
            qq3  = fmaf(xr, xr, fmaf(yr, yr, zr * zr));
            B3.u = make_uint4(packh2(hx, hy),
                              packh2(hz, (_Float16)0.0f) | 0x3C000000u, 0x3C00u, 0u);
        }
    }
    __syncthreads();

    // 32 tiles: 1 ds_read_b128 feeds 4 MFMAs; fminf-pair folds (compiler fuses to v_min3)
    float m0A = 3.4e38f, m0B = 3.4e38f, m1A = 3.4e38f, m1B = 3.4e38f;
    float m2A = 3.4e38f, m2B = 3.4e38f, m3A = 3.4e38f, m3B = 3.4e38f;
    const int c = lane & 31;

    // OPAQUE zero C-operand: without this, the allocator rematerializes the zero
    // vector into the (coalesced) MFMA destination before EVERY mfma -> 16 movs/MFMA
    // (R3: VALUBusy 54% = ~40 VALU/MFMA; R9: VGPR_Count 40 = accs shuttled).
    // The empty asm makes zc unknown -> kept live once, C != D, init hoisted.
    f32x16 zc = {};
    asm volatile("" : "+v"(zc));

    #pragma unroll 4
    for (int t = 0; t < RBLK / 32; ++t) {
        union { uint4 u; f16x8 h; } A;
        A.u = rA[t * 32 + c];
        f32x16 d0 = __builtin_amdgcn_mfma_f32_32x32x16_f16(A.h, B0.h, zc, 0, 0, 0);
        f32x16 d1 = __builtin_amdgcn_mfma_f32_32x32x16_f16(A.h, B1.h, zc, 0, 0, 0);
        f32x16 d2 = __builtin_amdgcn_mfma_f32_32x32x16_f16(A.h, B2.h, zc, 0, 0, 0);
        f32x16 d3 = __builtin_amdgcn_mfma_f32_32x32x16_f16(A.h, B3.h, zc, 0, 0, 0);
        m0A = fminf(fminf(d0[0],  d0[1]),  m0A);
        m0A = fminf(fminf(d0[2],  d0[3]),  m0A);
        m0A = fminf(fminf(d0[4],  d0[5]),  m0A);
        m0A = fminf(fminf(d0[6],  d0[7]),  m0A);
        m0B = fminf(fminf(d0[8],  d0[9]),  m0B);
        m0B = fminf(fminf(d0[10], d0[11]), m0B);
        m0B = fminf(fminf(d0[12], d0[13]), m0B);
        m0B = fminf(fminf(d0[14], d0[15]), m0B);
        m1A = fminf(fminf(d1[0],  d1[1]),  m1A);
        m1A = fminf(fminf(d1[2],  d1[3]),  m1A);
        m1A = fminf(fminf(d1[4],  d1[5]),  m1A);
        m1A = fminf(fminf(d1[6],  d1[7]),  m1A);
        m1B = fminf(fminf(d1[8],  d1[9]),  m1B);
        m1B = fminf(fminf(d1[10], d1[11]), m1B);
        m1B = fminf(fminf(d1[12], d1[13]), m1B);
        m1B = fminf(fminf(d1[14], d1[15]), m1B);
        m2A = fminf(fminf(d2[0],  d2[1]),  m2A);
        m2A = fminf(fminf(d2[2],  d2[3]),  m2A);
        m2A = fminf(fminf(d2[4],  d2[5]),  m2A);
        m2A = fminf(fminf(d2[6],  d2[7]),  m2A);
        m2B = fminf(fminf(d2[8],  d2[9]),  m2B);
        m2B = fminf(fminf(d2[10], d2[11]), m2B);
        m2B = fminf(fminf(d2[12], d2[13]), m2B);
        m2B = fminf(fminf(d2[14], d2[15]), m2B);
        m3A = fminf(fminf(d3[0],  d3[1]),  m3A);
        m3A = fminf(fminf(d3[2],  d3[3]),  m3A);
        m3A = fminf(fminf(d3[4],  d3[5]),  m3A);
        m3A = fminf(fminf(d3[6],  d3[7]),  m3A);
        m3B = fminf(fminf(d3[8],  d3[9]),  m3B);
        m3B = fminf(fminf(d3[10], d3[11]), m3B);
        m3B = fminf(fminf(d3[12], d3[13]), m3B);
        m3B = fminf(fminf(d3[14], d3[15]), m3B);
    }
    float m0 = fminf(m0A, m0B);
    float m1 = fminf(m1A, m1B);
    float m2 = fminf(m2A, m2B);
    float m3 = fminf(m3A, m3B);
    m0 = fminf(m0, __shfl_xor(m0, 32));       // fold the two 16-row halves
    m1 = fminf(m1, __shfl_xor(m1, 32));
    m2 = fminf(m2, __shfl_xor(m2, 32));
    m3 = fminf(m3, __shfl_xor(m3, 32));
    if (lane < 32) {
        float* dst = pmin + ((size_t)prob * RR + rr) * NPTS;
        dst[qid0] = m0 + qq0;                 // plain stores, no atomics
        dst[qid1] = m1 + qq1;
        dst[qid2] = m2 + qq2;
        dst[qid3] = m3 + qq3;
    }
}

// ---------------- pass 2: fold RR partial mins, clamp, deterministic global sum ----------------
__global__ __launch_bounds__(1024) void cd_pass2(const float* __restrict__ pmin,
                                                 unsigned long long* __restrict__ acc,
                                                 unsigned* __restrict__ cnt,
                                                 float* __restrict__ out) {
    const int g = blockIdx.x * 1024 + threadIdx.x;   // 64 blocks x 1024 = 65536 queries
    const int prob = g >> 13, qid = g & (NPTS - 1);
    const float* p = pmin + (size_t)prob * RR * NPTS + qid;
    float m = p[0];
    #pragma unroll
    for (int r = 1; r < RR; ++r) m = fminf(m, p[(size_t)r * NPTS]);
    float d = fmaxf(m, 0.0f);

    #pragma unroll
    for (int off = 32; off >= 1; off >>= 1) d += __shfl_xor(d, off);
    __shared__ float w[16];
    const int wave = threadIdx.x >> 6, lane = threadIdx.x & 63;
    if (lane == 0) w[wave] = d;
    __syncthreads();
    if (threadIdx.x == 0) {
        float t = 0.0f;
        #pragma unroll
        for (int i = 0; i < 16; ++i) t += w[i];
        // fixed-point (2^30) integer add: order-independent -> deterministic
        unsigned long long q = (unsigned long long)((double)t * 1073741824.0 + 0.5);
        atomicAdd(acc, q);
        __threadfence();
        unsigned old = atomicAdd(cnt, 1u);
        if (old == gridDim.x - 1) {           // last block finalizes
            unsigned long long v = atomicAdd(acc, 0ull);   // coherent read via RMW
            out[0] = (float)((double)v * (1.0 / 1073741824.0) * (0.5 / BATCH));
        }
    }
}

extern "C" void kernel_launch(void* const* d_in, const int* in_sizes, int n_in,
                              void* d_out, int out_size, void* d_ws, size_t ws_size,
                              hipStream_t stream) {
    const float* gen   = (const float*)d_in[0];   // [4,8192,3] f32
    const float* train = (const float*)d_in[1];   // [4,8192,3] f32
    char* ws = (char*)d_ws;
    float* pmin = (float*)ws;                                  // 2 MB partial mins
    unsigned long long* acc = (unsigned long long*)(ws + 0x200000);
    unsigned* cnt = (unsigned*)(ws + 0x200008);
    float* out = (float*)d_out;

    cd_pass1<<<dim3(NQB, RR, NPROB), TPB, 0, stream>>>(gen, train, pmin, acc, cnt);
    cd_pass2<<<64, 1024, 0, stream>>>(pmin, acc, cnt, out);
}

// Round 12
// 24.403 us; speedup vs baseline: 5.5738x; 1.0139x over previous
//
#include <hip/hip_runtime.h>

typedef _Float16 f16x8  __attribute__((ext_vector_type(8)));
typedef float    f32x16 __attribute__((ext_vector_type(16)));

static constexpr int BATCH = 4;
static constexpr int NPTS  = 8192;
static constexpr int NPROB = 2 * BATCH;       // (batch, direction) = 8
static constexpr int RR    = 8;               // ref chunks per problem
static constexpr int RBLK  = NPTS / RR;       // 1024 refs staged per block (16 KB)
static constexpr int TPB   = 256;             // 4 waves
static constexpr int WQ    = 128;             // queries per wave (4 MFMA col-groups)
static constexpr int QBLK  = (TPB / 64) * WQ; // 512 queries per block
static constexpr int NQB   = NPTS / QBLK;     // 16 query tiles

__device__ __forceinline__ unsigned packh2(_Float16 lo, _Float16 hi) {
    union { _Float16 h[2]; unsigned u; } v;
    v.h[0] = lo; v.h[1] = hi;
    return v.u;
}

// ---------------- pass 1: per-(qtile, refchunk, prob) partial NN min via MFMA ----------------
__global__ __launch_bounds__(TPB, 4) void cd_pass1(const float* __restrict__ gen,
                                                   const float* __restrict__ train,
                                                   float* __restrict__ pmin,
                                                   unsigned long long* __restrict__ acc,
                                                   unsigned* __restrict__ cnt) {
    __shared__ uint4 rA[RBLK];                // 16 KB packed refs (order-scrambled: min-safe)
    const int qb = blockIdx.x, rr = blockIdx.y, prob = blockIdx.z;
    if (qb == 0 && rr == 0 && prob == 0 && threadIdx.x == 0) { *acc = 0ull; *cnt = 0u; }
    const int b = prob >> 1, dir = prob & 1;
    const float* qbase = (dir == 0 ? gen : train) + (size_t)b * NPTS * 3;
    const float* rbase = (dir == 0 ? train : gen) + (size_t)b * NPTS * 3;
    const int lane = threadIdx.x & 63, wave = threadIdx.x >> 6;

    // Stage+pack: thread t loads 4 consecutive points (12 floats, float4-aligned),
    // writes TRANSPOSED rA[i*256+t] -> consecutive lanes hit consecutive 16B slots
    // (conflict-free ds_write_b128). Point order in LDS is permuted - fine for min.
    {
        const float4* s4 = (const float4*)(rbase + rr * (RBLK * 3)) + threadIdx.x * 3;
        const float4 v0 = s4[0], v1 = s4[1], v2 = s4[2];
        const float px[4] = {v0.x, v0.w, v1.z, v2.y};
        const float py[4] = {v0.y, v1.x, v1.w, v2.z};
        const float pz[4] = {v0.z, v1.y, v2.x, v2.w};
        #pragma unroll
        for (int i = 0; i < 4; ++i) {
            const _Float16 hx = (_Float16)px[i], hy = (_Float16)py[i], hz = (_Float16)pz[i];
            const float xr = (float)hx, yr = (float)hy, zr = (float)hz;   // exact
            const float yy = fmaf(xr, xr, fmaf(yr, yr, zr * zr));
            const _Float16 yh = (_Float16)yy;
            const _Float16 yl = (_Float16)(yy - (float)yh);               // hi/lo split
            rA[i * TPB + threadIdx.x] =
                make_uint4(packh2((_Float16)(-2.0f * xr), (_Float16)(-2.0f * yr)),
                           packh2((_Float16)(-2.0f * zr), yh),
                           packh2(yl, (_Float16)0.0f), 0u);
        }
    }

    // Four query fragments per wave: 32 queries each; B k-vec = [qx,qy,qz,1,1,0,0,0]
    const int qid0 = qb * QBLK + wave * WQ + (lane & 31);
    const int qid1 = qid0 + 32, qid2 = qid0 + 64, qid3 = qid0 + 96;
    float qq0 = 0.0f, qq1 = 0.0f, qq2 = 0.0f, qq3 = 0.0f;
    union { uint4 u; f16x8 h; } B0, B1, B2, B3;
    B0.u = make_uint4(0u, 0u, 0u, 0u);
    B1.u = make_uint4(0u, 0u, 0u, 0u);
    B2.u = make_uint4(0u, 0u, 0u, 0u);
    B3.u = make_uint4(0u, 0u, 0u, 0u);
    if (lane < 32) {
        {
            const float qx = qbase[qid0*3+0], qy = qbase[qid0*3+1], qz = qbase[qid0*3+2];
            const _Float16 hx = (_Float16)qx, hy = (_Float16)qy, hz = (_Float16)qz;
            const float xr = (float)hx, yr = (float)hy, zr = (float)hz;
            qq0  = fmaf(xr, xr, fmaf(yr, yr, zr * zr));
            B0.u = make_uint4(packh2(hx, hy),
                              packh2(hz, (_Float16)0.0f) | 0x3C000000u, 0x3C00u, 0u);
        }
        {
            const float qx = qbase[qid1*3+0], qy = qbase[qid1*3+1], qz = qbase[qid1*3+2];
            const _Float16 hx = (_Float16)qx, hy = (_Float16)qy, hz = (_Float16)qz;
            const float xr = (float)hx, yr = (float)hy, zr = (float)hz;
            qq1  = fmaf(xr, xr, fmaf(yr, yr, zr * zr));
            B1.u = make_uint4(packh2(hx, hy),
                              packh2(hz, (_Float16)0.0f) | 0x3C000000u, 0x3C00u, 0u);
        }
        {
            const float qx = qbase[qid2*3+0], qy = qbase[qid2*3+1], qz = qbase[qid2*3+2];
            const _Float16 hx = (_Float16)qx, hy = (_Float16)qy, hz = (_Float16)qz;
            const float xr = (float)hx, yr = (float)hy, zr = (float)hz;
            qq2  = fmaf(xr, xr, fmaf(yr, yr, zr * zr));
            B2.u = make_uint4(packh2(hx, hy),
                              packh2(hz, (_Float16)0.0f) | 0x3C000000u, 0x3C00u, 0u);
        }
        {
            const float qx = qbase[qid3*3+0], qy = qbase[qid3*3+1], qz = qbase[qid3*3+2];
            const _Float16 hx = (_Float16)qx, hy = (_Float16)qy, hz = (_Float16)qz;
            const float xr = (float)hx, yr = (float)hy, zr = (float)hz;
            qq3  = fmaf(xr, xr, fmaf(yr, yr, zr * zr));
            B3.u = make_uint4(packh2(hx, hy),
                              packh2(hz, (_Float16)0.0f) | 0x3C000000u, 0x3C00u, 0u);
        }
    }
    __syncthreads();

    // 32 tiles: 1 ds_read_b128 feeds 4 MFMAs. SEQUENCED: mfma -> fold -> sched_barrier
    // so only ONE f32x16 result is live at a time -> results stay in arch VGPRs and
    // the v_accvgpr_read shuttle (R3: ~16 extra VALU/MFMA, 64% of VALU traffic) dies.
    float m0A = 3.4e38f, m0B = 3.4e38f, m1A = 3.4e38f, m1B = 3.4e38f;
    float m2A = 3.4e38f, m2B = 3.4e38f, m3A = 3.4e38f, m3B = 3.4e38f;
    const int c = lane & 31;
    const f32x16 zc = {};
    #pragma unroll 4
    for (int t = 0; t < RBLK / 32; ++t) {
        union { uint4 u; f16x8 h; } A;
        A.u = rA[t * 32 + c];
        f32x16 d;

        d = __builtin_amdgcn_mfma_f32_32x32x16_f16(A.h, B0.h, zc, 0, 0, 0);
        m0A = fminf(fminf(d[0],  d[1]),  m0A);
        m0A = fminf(fminf(d[2],  d[3]),  m0A);
        m0A = fminf(fminf(d[4],  d[5]),  m0A);
        m0A = fminf(fminf(d[6],  d[7]),  m0A);
        m0B = fminf(fminf(d[8],  d[9]),  m0B);
        m0B = fminf(fminf(d[10], d[11]), m0B);
        m0B = fminf(fminf(d[12], d[13]), m0B);
        m0B = fminf(fminf(d[14], d[15]), m0B);
        __builtin_amdgcn_sched_barrier(0);

        d = __builtin_amdgcn_mfma_f32_32x32x16_f16(A.h, B1.h, zc, 0, 0, 0);
        m1A = fminf(fminf(d[0],  d[1]),  m1A);
        m1A = fminf(fminf(d[2],  d[3]),  m1A);
        m1A = fminf(fminf(d[4],  d[5]),  m1A);
        m1A = fminf(fminf(d[6],  d[7]),  m1A);
        m1B = fminf(fminf(d[8],  d[9]),  m1B);
        m1B = fminf(fminf(d[10], d[11]), m1B);
        m1B = fminf(fminf(d[12], d[13]), m1B);
        m1B = fminf(fminf(d[14], d[15]), m1B);
        __builtin_amdgcn_sched_barrier(0);

        d = __builtin_amdgcn_mfma_f32_32x32x16_f16(A.h, B2.h, zc, 0, 0, 0);
        m2A = fminf(fminf(d[0],  d[1]),  m2A);
        m2A = fminf(fminf(d[2],  d[3]),  m2A);
        m2A = fminf(fminf(d[4],  d[5]),  m2A);
        m2A = fminf(fminf(d[6],  d[7]),  m2A);
        m2B = fminf(fminf(d[8],  d[9]),  m2B);
        m2B = fminf(fminf(d[10], d[11]), m2B);
        m2B = fminf(fminf(d[12], d[13]), m2B);
        m2B = fminf(fminf(d[14], d[15]), m2B);
        __builtin_amdgcn_sched_barrier(0);

        d = __builtin_amdgcn_mfma_f32_32x32x16_f16(A.h, B3.h, zc, 0, 0, 0);
        m3A = fminf(fminf(d[0],  d[1]),  m3A);
        m3A = fminf(fminf(d[2],  d[3]),  m3A);
        m3A = fminf(fminf(d[4],  d[5]),  m3A);
        m3A = fminf(fminf(d[6],  d[7]),  m3A);
        m3B = fminf(fminf(d[8],  d[9]),  m3B);
        m3B = fminf(fminf(d[10], d[11]), m3B);
        m3B = fminf(fminf(d[12], d[13]), m3B);
        m3B = fminf(fminf(d[14], d[15]), m3B);
        // no barrier here: let next tile's ds_read hoist over this fold
    }
    float m0 = fminf(m0A, m0B);
    float m1 = fminf(m1A, m1B);
    float m2 = fminf(m2A, m2B);
    float m3 = fminf(m3A, m3B);
    m0 = fminf(m0, __shfl_xor(m0, 32));       // fold the two 16-row halves
    m1 = fminf(m1, __shfl_xor(m1, 32));
    m2 = fminf(m2, __shfl_xor(m2, 32));
    m3 = fminf(m3, __shfl_xor(m3, 32));
    if (lane < 32) {
        float* dst = pmin + ((size_t)prob * RR + rr) * NPTS;
        dst[qid0] = m0 + qq0;                 // plain stores, no atomics
        dst[qid1] = m1 + qq1;
        dst[qid2] = m2 + qq2;
        dst[qid3] = m3 + qq3;
    }
}

// ---------------- pass 2: fold RR partial mins, clamp, deterministic global sum ----------------
__global__ __launch_bounds__(1024) void cd_pass2(const float* __restrict__ pmin,
                                                 unsigned long long* __restrict__ acc,
                                                 unsigned* __restrict__ cnt,
                                                 float* __restrict__ out) {
    const int g = blockIdx.x * 1024 + threadIdx.x;   // 64 blocks x 1024 = 65536 queries
    const int prob = g >> 13, qid = g & (NPTS - 1);
    const float* p = pmin + (size_t)prob * RR * NPTS + qid;
    float m = p[0];
    #pragma unroll
    for (int r = 1; r < RR; ++r) m = fminf(m, p[(size_t)r * NPTS]);
    float d = fmaxf(m, 0.0f);

    #pragma unroll
    for (int off = 32; off >= 1; off >>= 1) d += __shfl_xor(d, off);
    __shared__ float w[16];
    const int wave = threadIdx.x >> 6, lane = threadIdx.x & 63;
    if (lane == 0) w[wave] = d;
    __syncthreads();
    if (threadIdx.x == 0) {
        float t = 0.0f;
        #pragma unroll
        for (int i = 0; i < 16; ++i) t += w[i];
        // fixed-point (2^30) integer add: order-independent -> deterministic
        unsigned long long q = (unsigned long long)((double)t * 1073741824.0 + 0.5);
        atomicAdd(acc, q);
        __threadfence();
        unsigned old = atomicAdd(cnt, 1u);
        if (old == gridDim.x - 1) {           // last block finalizes
            unsigned long long v = atomicAdd(acc, 0ull);   // coherent read via RMW
            out[0] = (float)((double)v * (1.0 / 1073741824.0) * (0.5 / BATCH));
        }
    }
}

extern "C" void kernel_launch(void* const* d_in, const int* in_sizes, int n_in,
                              void* d_out, int out_size, void* d_ws, size_t ws_size,
                              hipStream_t stream) {
    const float* gen   = (const float*)d_in[0];   // [4,8192,3] f32
    const float* train = (const float*)d_in[1];   // [4,8192,3] f32
    char* ws = (char*)d_ws;
    float* pmin = (float*)ws;                                  // 2 MB partial mins
    unsigned long long* acc = (unsigned long long*)(ws + 0x200000);
    unsigned* cnt = (unsigned*)(ws + 0x200008);
    float* out = (float*)d_out;

    cd_pass1<<<dim3(NQB, RR, NPROB), TPB, 0, stream>>>(gen, train, pmin, acc, cnt);
    cd_pass2<<<64, 1024, 0, stream>>>(pmin, acc, cnt, out);
}

// Round 13
// 24.292 us; speedup vs baseline: 5.5994x; 1.0046x over previous
//
#include <hip/hip_runtime.h>

typedef _Float16 f16x8  __attribute__((ext_vector_type(8)));
typedef float    f32x16 __attribute__((ext_vector_type(16)));

static constexpr int BATCH = 4;
static constexpr int NPTS  = 8192;
static constexpr int NPROB = 2 * BATCH;       // (batch, direction) = 8
static constexpr int RR    = 8;               // ref chunks per problem
static constexpr int RBLK  = NPTS / RR;       // 1024 refs staged per block (16 KB)
static constexpr int TPB   = 256;             // 4 waves
static constexpr int WQ    = 128;             // queries per wave (4 MFMA col-groups)
static constexpr int QBLK  = (TPB / 64) * WQ; // 512 queries per block
static constexpr int NQB   = NPTS / QBLK;     // 16 query tiles

__device__ __forceinline__ unsigned packh2(_Float16 lo, _Float16 hi) {
    union { _Float16 h[2]; unsigned u; } v;
    v.h[0] = lo; v.h[1] = hi;
    return v.u;
}

// fold one MFMA result tile into a frag's two running-min chains (8 pair-min ops)
#define FOLD(d, mA, mB)                                   \
    do {                                                  \
        mA = fminf(fminf((d)[0],  (d)[1]),  mA);          \
        mA = fminf(fminf((d)[2],  (d)[3]),  mA);          \
        mA = fminf(fminf((d)[4],  (d)[5]),  mA);          \
        mA = fminf(fminf((d)[6],  (d)[7]),  mA);          \
        mB = fminf(fminf((d)[8],  (d)[9]),  mB);          \
        mB = fminf(fminf((d)[10], (d)[11]), mB);          \
        mB = fminf(fminf((d)[12], (d)[13]), mB);          \
        mB = fminf(fminf((d)[14], (d)[15]), mB);          \
    } while (0)

// ---------------- pass 1: per-(qtile, refchunk, prob) partial NN min via MFMA ----------------
__global__ __launch_bounds__(TPB, 4) void cd_pass1(const float* __restrict__ gen,
                                                   const float* __restrict__ train,
                                                   float* __restrict__ pmin,
                                                   unsigned long long* __restrict__ acc,
                                                   unsigned* __restrict__ cnt) {
    __shared__ uint4 rA[RBLK];                // 16 KB packed refs (order-scrambled: min-safe)
    const int qb = blockIdx.x, rr = blockIdx.y, prob = blockIdx.z;
    if (qb == 0 && rr == 0 && prob == 0 && threadIdx.x == 0) { *acc = 0ull; *cnt = 0u; }
    const int b = prob >> 1, dir = prob & 1;
    const float* qbase = (dir == 0 ? gen : train) + (size_t)b * NPTS * 3;
    const float* rbase = (dir == 0 ? train : gen) + (size_t)b * NPTS * 3;
    const int lane = threadIdx.x & 63, wave = threadIdx.x >> 6;

    // Stage+pack: thread t loads 4 consecutive points (12 floats, float4-aligned),
    // writes TRANSPOSED rA[i*256+t] -> consecutive lanes hit consecutive 16B slots
    // (conflict-free ds_write_b128). Point order in LDS is permuted - fine for min.
    {
        const float4* s4 = (const float4*)(rbase + rr * (RBLK * 3)) + threadIdx.x * 3;
        const float4 v0 = s4[0], v1 = s4[1], v2 = s4[2];
        const float px[4] = {v0.x, v0.w, v1.z, v2.y};
        const float py[4] = {v0.y, v1.x, v1.w, v2.z};
        const float pz[4] = {v0.z, v1.y, v2.x, v2.w};
        #pragma unroll
        for (int i = 0; i < 4; ++i) {
            const _Float16 hx = (_Float16)px[i], hy = (_Float16)py[i], hz = (_Float16)pz[i];
            const float xr = (float)hx, yr = (float)hy, zr = (float)hz;   // exact
            const float yy = fmaf(xr, xr, fmaf(yr, yr, zr * zr));
            const _Float16 yh = (_Float16)yy;
            const _Float16 yl = (_Float16)(yy - (float)yh);               // hi/lo split
            rA[i * TPB + threadIdx.x] =
                make_uint4(packh2((_Float16)(-2.0f * xr), (_Float16)(-2.0f * yr)),
                           packh2((_Float16)(-2.0f * zr), yh),
                           packh2(yl, (_Float16)0.0f), 0u);
        }
    }

    // Four query fragments per wave: 32 queries each; B k-vec = [qx,qy,qz,1,1,0,0,0]
    const int qid0 = qb * QBLK + wave * WQ + (lane & 31);
    const int qid1 = qid0 + 32, qid2 = qid0 + 64, qid3 = qid0 + 96;
    float qq0 = 0.0f, qq1 = 0.0f, qq2 = 0.0f, qq3 = 0.0f;
    union { uint4 u; f16x8 h; } B0, B1, B2, B3;
    B0.u = make_uint4(0u, 0u, 0u, 0u);
    B1.u = make_uint4(0u, 0u, 0u, 0u);
    B2.u = make_uint4(0u, 0u, 0u, 0u);
    B3.u = make_uint4(0u, 0u, 0u, 0u);
    if (lane < 32) {
        {
            const float qx = qbase[qid0*3+0], qy = qbase[qid0*3+1], qz = qbase[qid0*3+2];
            const _Float16 hx = (_Float16)qx, hy = (_Float16)qy, hz = (_Float16)qz;
            const float xr = (float)hx, yr = (float)hy, zr = (float)hz;
            qq0  = fmaf(xr, xr, fmaf(yr, yr, zr * zr));
            B0.u = make_uint4(packh2(hx, hy),
                              packh2(hz, (_Float16)0.0f) | 0x3C000000u, 0x3C00u, 0u);
        }
        {
            const float qx = qbase[qid1*3+0], qy = qbase[qid1*3+1], qz = qbase[qid1*3+2];
            const _Float16 hx = (_Float16)qx, hy = (_Float16)qy, hz = (_Float16)qz;
            const float xr = (float)hx, yr = (float)hy, zr = (float)hz;
            qq1  = fmaf(xr, xr, fmaf(yr, yr, zr * zr));
            B1.u = make_uint4(packh2(hx, hy),
                              packh2(hz, (_Float16)0.0f) | 0x3C000000u, 0x3C00u, 0u);
        }
        {
            const float qx = qbase[qid2*3+0], qy = qbase[qid2*3+1], qz = qbase[qid2*3+2];
            const _Float16 hx = (_Float16)qx, hy = (_Float16)qy, hz = (_Float16)qz;
            const float xr = (float)hx, yr = (float)hy, zr = (float)hz;
            qq2  = fmaf(xr, xr, fmaf(yr, yr, zr * zr));
            B2.u = make_uint4(packh2(hx, hy),
                              packh2(hz, (_Float16)0.0f) | 0x3C000000u, 0x3C00u, 0u);
        }
        {
            const float qx = qbase[qid3*3+0], qy = qbase[qid3*3+1], qz = qbase[qid3*3+2];
            const _Float16 hx = (_Float16)qx, hy = (_Float16)qy, hz = (_Float16)qz;
            const float xr = (float)hx, yr = (float)hy, zr = (float)hz;
            qq3  = fmaf(xr, xr, fmaf(yr, yr, zr * zr));
            B3.u = make_uint4(packh2(hx, hy),
                              packh2(hz, (_Float16)0.0f) | 0x3C000000u, 0x3C00u, 0u);
        }
    }
    __syncthreads();

    // SOFTWARE-PIPELINED fold: each region issues the NEXT independent MFMA first,
    // then folds the PREVIOUS result (now latency-covered). In-order issue means the
    // naive (mfma -> dependent fold) order stalls the wave at every fold and blocks
    // the next MFMA (R7/R10/R11 all ~24.3us). Fold order per chain is unchanged ->
    // bit-identical result.
    float m0A = 3.4e38f, m0B = 3.4e38f, m1A = 3.4e38f, m1B = 3.4e38f;
    float m2A = 3.4e38f, m2B = 3.4e38f, m3A = 3.4e38f, m3B = 3.4e38f;
    const int c = lane & 31;
    const f32x16 zc = {};
    union { uint4 u; f16x8 h; } A0, A1;

    A0.u = rA[c];                                            // tile 0 A-fragment
    f32x16 dP = __builtin_amdgcn_mfma_f32_32x32x16_f16(A0.h, B0.h, zc, 0, 0, 0);

    #pragma unroll 4
    for (int t = 0; t < RBLK / 32 - 1; ++t) {
        f32x16 d1 = __builtin_amdgcn_mfma_f32_32x32x16_f16(A0.h, B1.h, zc, 0, 0, 0);
        FOLD(dP, m0A, m0B);                                  // fold B0 @ tile t
        __builtin_amdgcn_sched_barrier(0);
        f32x16 d2 = __builtin_amdgcn_mfma_f32_32x32x16_f16(A0.h, B2.h, zc, 0, 0, 0);
        FOLD(d1, m1A, m1B);
        __builtin_amdgcn_sched_barrier(0);
        f32x16 d3 = __builtin_amdgcn_mfma_f32_32x32x16_f16(A0.h, B3.h, zc, 0, 0, 0);
        FOLD(d2, m2A, m2B);
        __builtin_amdgcn_sched_barrier(0);
        A1.u = rA[(t + 1) * 32 + c];                         // next tile A-fragment
        dP = __builtin_amdgcn_mfma_f32_32x32x16_f16(A1.h, B0.h, zc, 0, 0, 0);
        FOLD(d3, m3A, m3B);
        __builtin_amdgcn_sched_barrier(0);
        A0.u = A1.u;
    }
    // epilogue: tile 31 (dP already holds B0 @ 31)
    {
        f32x16 e1 = __builtin_amdgcn_mfma_f32_32x32x16_f16(A0.h, B1.h, zc, 0, 0, 0);
        FOLD(dP, m0A, m0B);
        __builtin_amdgcn_sched_barrier(0);
        f32x16 e2 = __builtin_amdgcn_mfma_f32_32x32x16_f16(A0.h, B2.h, zc, 0, 0, 0);
        FOLD(e1, m1A, m1B);
        __builtin_amdgcn_sched_barrier(0);
        f32x16 e3 = __builtin_amdgcn_mfma_f32_32x32x16_f16(A0.h, B3.h, zc, 0, 0, 0);
        FOLD(e2, m2A, m2B);
        __builtin_amdgcn_sched_barrier(0);
        FOLD(e3, m3A, m3B);
    }

    float m0 = fminf(m0A, m0B);
    float m1 = fminf(m1A, m1B);
    float m2 = fminf(m2A, m2B);
    float m3 = fminf(m3A, m3B);
    m0 = fminf(m0, __shfl_xor(m0, 32));       // fold the two 16-row halves
    m1 = fminf(m1, __shfl_xor(m1, 32));
    m2 = fminf(m2, __shfl_xor(m2, 32));
    m3 = fminf(m3, __shfl_xor(m3, 32));
    if (lane < 32) {
        float* dst = pmin + ((size_t)prob * RR + rr) * NPTS;
        dst[qid0] = m0 + qq0;                 // plain stores, no atomics
        dst[qid1] = m1 + qq1;
        dst[qid2] = m2 + qq2;
        dst[qid3] = m3 + qq3;
    }
}

// ---------------- pass 2: fold RR partial mins, clamp, deterministic global sum ----------------
__global__ __launch_bounds__(1024) void cd_pass2(const float* __restrict__ pmin,
                                                 unsigned long long* __restrict__ acc,
                                                 unsigned* __restrict__ cnt,
                                                 float* __restrict__ out) {
    const int g = blockIdx.x * 1024 + threadIdx.x;   // 64 blocks x 1024 = 65536 queries
    const int prob = g >> 13, qid = g & (NPTS - 1);
    const float* p = pmin + (size_t)prob * RR * NPTS + qid;
    float m = p[0];
    #pragma unroll
    for (int r = 1; r < RR; ++r) m = fminf(m, p[(size_t)r * NPTS]);
    float d = fmaxf(m, 0.0f);

    #pragma unroll
    for (int off = 32; off >= 1; off >>= 1) d += __shfl_xor(d, off);
    __shared__ float w[16];
    const int wave = threadIdx.x >> 6, lane = threadIdx.x & 63;
    if (lane == 0) w[wave] = d;
    __syncthreads();
    if (threadIdx.x == 0) {
        float t = 0.0f;
        #pragma unroll
        for (int i = 0; i < 16; ++i) t += w[i];
        // fixed-point (2^30) integer add: order-independent -> deterministic
        unsigned long long q = (unsigned long long)((double)t * 1073741824.0 + 0.5);
        atomicAdd(acc, q);
        __threadfence();
        unsigned old = atomicAdd(cnt, 1u);
        if (old == gridDim.x - 1) {           // last block finalizes
            unsigned long long v = atomicAdd(acc, 0ull);   // coherent read via RMW
            out[0] = (float)((double)v * (1.0 / 1073741824.0) * (0.5 / BATCH));
        }
    }
}

extern "C" void kernel_launch(void* const* d_in, const int* in_sizes, int n_in,
                              void* d_out, int out_size, void* d_ws, size_t ws_size,
                              hipStream_t stream) {
    const float* gen   = (const float*)d_in[0];   // [4,8192,3] f32
    const float* train = (const float*)d_in[1];   // [4,8192,3] f32
    char* ws = (char*)d_ws;
    float* pmin = (float*)ws;                                  // 2 MB partial mins
    unsigned long long* acc = (unsigned long long*)(ws + 0x200000);
    unsigned* cnt = (unsigned*)(ws + 0x200008);
    float* out = (float*)d_out;

    cd_pass1<<<dim3(NQB, RR, NPROB), TPB, 0, stream>>>(gen, train, pmin, acc, cnt);
    cd_pass2<<<64, 1024, 0, stream>>>(pmin, acc, cnt, out);
}